// Round 5
// baseline (230.688 us; speedup 1.0000x reference)
//
#include <hip/hip_runtime.h>
#include <math.h>

// Causal SDPA, B=4 H=8 S=2048 D=64, scale = 1/sqrt(512)  (HIDDEN_SIZE=512).
// d_out (fp32): [B,H,S,D] output O followed by [B,H,S,S] attn probs P.
// Inputs fp32. mask input ignored (statically causal, triu k=1).
//
// Swapped QK^T (mfma(K,Q) -> S^T): lane owns one q-row -> float4 P stores,
// 2-shuffle softmax reduce. This round: double-buffered LDS with
// issue-early/write-late staging and ONE barrier per tile (T3 min-2-phase).

#define S_LEN 2048
#define SCALE 0.04419417382415922f  // 1/sqrt(512)

typedef __attribute__((ext_vector_type(8))) short bf16x8;
typedef __attribute__((ext_vector_type(4))) short bf16x4;
typedef __attribute__((ext_vector_type(4))) float f32x4;

__device__ __forceinline__ short f2bf(float f) {
  unsigned u = __builtin_bit_cast(unsigned, f);
  u = (u + 0x7FFFu + ((u >> 16) & 1u)) >> 16;
  return (short)u;
}

__device__ __forceinline__ bf16x8 pack8(float4 a, float4 b) {
  bf16x8 t;
  t[0] = f2bf(a.x); t[1] = f2bf(a.y); t[2] = f2bf(a.z); t[3] = f2bf(a.w);
  t[4] = f2bf(b.x); t[5] = f2bf(b.y); t[6] = f2bf(b.z); t[7] = f2bf(b.w);
  return t;
}

// LDS rows padded to 72 halfs (144 B): 16B-aligned rows, bank-group rotation.
__global__ __launch_bounds__(256, 2)
void sdpa_kernel(const float* Q, const float* K, const float* V,
                 float* outO, float* outP)
{
  __shared__ __align__(16) short ldsK[2][64][72];   // K tile   [k][d], dbuf
  __shared__ __align__(16) short ldsV[2][64][72];   // V^T tile [d][k], dbuf
  __shared__ __align__(16) short ldsP[4][16][72];   // per-wave P tile [q][k]

  const int tid  = threadIdx.x;
  const int lane = tid & 63;
  const int w    = tid >> 6;
  const int lrow = lane & 15;   // q-row lane index (S^T cols / O d-cols)
  const int lgrp = lane >> 4;

  // heavy q-tiles first: no load-imbalance tail
  const int qt = 31 - (blockIdx.x >> 5);
  const int bh = blockIdx.x & 31;
  const int q0 = qt << 6;
  const int qrow = q0 + (w << 4) + lrow;   // this lane's q row

  // staging map: thread covers tile row sr, 16 floats from col sc
  const int sr = tid & 63;
  const int sc = (tid >> 6) << 4;

  const float* Kbase = K + (size_t)bh * S_LEN * 64;
  const float* Vbase = V + (size_t)bh * S_LEN * 64;

  // Q fragment (B operand of S^T = K*Q^T): lane holds Q[qrow][ks*32+lgrp*8..+7]
  bf16x8 qf[2];
  {
    const float* qb = Q + ((size_t)(bh * S_LEN + qrow)) * 64;
#pragma unroll
    for (int ks = 0; ks < 2; ++ks) {
      const float* p = qb + ks * 32 + lgrp * 8;
      qf[ks] = pack8(*(const float4*)p, *(const float4*)(p + 4));
    }
  }

  float m_run = -INFINITY;
  float l_run = 0.f;

  float4 kr0, kr1, kr2, kr3;   // K prefetch regs
  float4 vr0, vr1, vr2, vr3;   // V prefetch regs

#define LOADK(t) {                                                            \
    const float* s_ = Kbase + ((size_t)(((t) << 6) + sr)) * 64 + sc;          \
    kr0 = ((const float4*)s_)[0]; kr1 = ((const float4*)s_)[1];               \
    kr2 = ((const float4*)s_)[2]; kr3 = ((const float4*)s_)[3]; }
#define WRITEK(b) {                                                           \
    *(bf16x8*)&ldsK[b][sr][sc]     = pack8(kr0, kr1);                         \
    *(bf16x8*)&ldsK[b][sr][sc + 8] = pack8(kr2, kr3); }
#define LOADV(t) {                                                            \
    const float* s_ = Vbase + ((size_t)(((t) << 6) + sr)) * 64 + sc;          \
    vr0 = ((const float4*)s_)[0]; vr1 = ((const float4*)s_)[1];               \
    vr2 = ((const float4*)s_)[2]; vr3 = ((const float4*)s_)[3]; }
#define WRITEV(b) {                                                           \
    const float vv_[16] = {vr0.x, vr0.y, vr0.z, vr0.w, vr1.x, vr1.y, vr1.z,   \
                           vr1.w, vr2.x, vr2.y, vr2.z, vr2.w, vr3.x, vr3.y,   \
                           vr3.z, vr3.w};                                     \
    _Pragma("unroll")                                                         \
    for (int j_ = 0; j_ < 16; ++j_) ldsV[b][sc + j_][sr] = f2bf(vv_[j_]); }

#define QKT(accv, buf)                                                        \
  _Pragma("unroll")                                                           \
  for (int nt = 0; nt < 4; ++nt) {                                            \
    f32x4 a_ = {0.f, 0.f, 0.f, 0.f};                                          \
    _Pragma("unroll")                                                         \
    for (int ks = 0; ks < 2; ++ks) {                                          \
      bf16x8 kf_ = *(const bf16x8*)&ldsK[buf][nt * 16 + lrow][ks * 32 + lgrp * 8]; \
      a_ = __builtin_amdgcn_mfma_f32_16x16x32_bf16(kf_, qf[ks], a_, 0, 0, 0); \
    }                                                                         \
    accv[nt] = a_;                                                            \
  }

#define MASKSCALE(accv, kt)                                                   \
  if ((kt) == qt) {                                                           \
    _Pragma("unroll")                                                         \
    for (int nt = 0; nt < 4; ++nt)                                            \
      _Pragma("unroll")                                                       \
      for (int rg = 0; rg < 4; ++rg) {                                        \
        const int col = ((kt) << 6) + nt * 16 + (lgrp << 2) + rg;             \
        accv[nt][rg] = (col > qrow) ? -INFINITY : accv[nt][rg] * SCALE;       \
      }                                                                       \
  } else {                                                                    \
    _Pragma("unroll")                                                         \
    for (int nt = 0; nt < 4; ++nt)                                            \
      _Pragma("unroll")                                                       \
      for (int rg = 0; rg < 4; ++rg) accv[nt][rg] *= SCALE;                   \
  }

  // ================= pass 1: exact row max + denominator =================
  LOADK(0)
  WRITEK(0)
  __syncthreads();
  int cur = 0;
  for (int kt = 0; kt <= qt; ++kt) {
    if (kt < qt) LOADK(kt + 1)          // issue-early: hides under compute

    f32x4 acc[4];
    QKT(acc, cur)
    MASKSCALE(acc, kt)

    float tm = -INFINITY;
#pragma unroll
    for (int nt = 0; nt < 4; ++nt)
#pragma unroll
      for (int rg = 0; rg < 4; ++rg) tm = fmaxf(tm, acc[nt][rg]);
    tm = fmaxf(tm, __shfl_xor(tm, 16));
    tm = fmaxf(tm, __shfl_xor(tm, 32));
    const float nm = fmaxf(m_run, tm);

    float ps = 0.f;
#pragma unroll
    for (int nt = 0; nt < 4; ++nt)
#pragma unroll
      for (int rg = 0; rg < 4; ++rg) ps += __expf(acc[nt][rg] - nm);
    ps += __shfl_xor(ps, 16);
    ps += __shfl_xor(ps, 32);

    l_run = l_run * __expf(m_run - nm) + ps;
    m_run = nm;

    if (kt < qt) WRITEK(cur ^ 1)        // write-late into alternate buffer
    __syncthreads();                    // ONE barrier per tile
    cur ^= 1;
  }

  const float inv_l = 1.f / l_run;

  f32x4 oacc[4];
#pragma unroll
  for (int nt = 0; nt < 4; ++nt) oacc[nt] = (f32x4){0.f, 0.f, 0.f, 0.f};

  const size_t pbase = (size_t)bh * S_LEN * S_LEN + (size_t)qrow * S_LEN;

  // ================= pass 2: probs, attn store, PV =================
  LOADK(0)
  LOADV(0)
  WRITEK(0)
  WRITEV(0)
  __syncthreads();
  cur = 0;
  for (int kt = 0; kt <= qt; ++kt) {
    if (kt < qt) { LOADK(kt + 1) LOADV(kt + 1) }   // issue-early

    f32x4 acc[4];
    QKT(acc, cur)
    MASKSCALE(acc, kt)

    // probabilities: float4 global store + b64 LDS store per nt
#pragma unroll
    for (int nt = 0; nt < 4; ++nt) {
      float4 p4;
      p4.x = __expf(acc[nt][0] - m_run) * inv_l;
      p4.y = __expf(acc[nt][1] - m_run) * inv_l;
      p4.z = __expf(acc[nt][2] - m_run) * inv_l;
      p4.w = __expf(acc[nt][3] - m_run) * inv_l;
      *(float4*)(outP + pbase + (kt << 6) + nt * 16 + (lgrp << 2)) = p4;
      bf16x4 pb;
      pb[0] = f2bf(p4.x); pb[1] = f2bf(p4.y);
      pb[2] = f2bf(p4.z); pb[3] = f2bf(p4.w);
      *(bf16x4*)&ldsP[w][lrow][nt * 16 + (lgrp << 2)] = pb;
    }

    // PV: A = own-wave P tile (16q x 64k), B = V^T tile (same-wave LDS
    // write->read; ldsP[w] is wave-private, ordered by lgkmcnt).
#pragma unroll
    for (int nt = 0; nt < 4; ++nt) {
#pragma unroll
      for (int ks = 0; ks < 2; ++ks) {
        bf16x8 pa = *(const bf16x8*)&ldsP[w][lrow][ks * 32 + lgrp * 8];
        bf16x8 vb = *(const bf16x8*)&ldsV[cur][nt * 16 + lrow][ks * 32 + lgrp * 8];
        oacc[nt] = __builtin_amdgcn_mfma_f32_16x16x32_bf16(pa, vb, oacc[nt], 0, 0, 0);
      }
    }

    if (kt < qt) { WRITEK(cur ^ 1) WRITEV(cur ^ 1) }  // write-late
    __syncthreads();                                   // ONE barrier per tile
    cur ^= 1;
  }

  // ---- zero the strictly-masked column range (cols >= (qt+1)*64) ----
  {
    const int kz = (qt + 1) << 6;
    if (kz < S_LEN) {
      const float4 z = {0.f, 0.f, 0.f, 0.f};
      for (int row = 0; row < 64; ++row) {
        const size_t base = (size_t)bh * S_LEN * S_LEN + (size_t)(q0 + row) * S_LEN;
        for (int c = kz + (tid << 2); c < S_LEN; c += 256 * 4) {
          *(float4*)(outP + base + c) = z;
        }
      }
    }
  }

  // ---- write O (fp32): O row = q0+16w+4*lgrp+rg, col d = nt*16+lrow ----
#pragma unroll
  for (int nt = 0; nt < 4; ++nt) {
#pragma unroll
    for (int rg = 0; rg < 4; ++rg) {
      const int rl = (lgrp << 2) + rg;
      const int d  = nt * 16 + lrow;
      outO[((size_t)(bh * S_LEN + q0 + (w << 4) + rl)) * 64 + d] = oacc[nt][rg];
    }
  }
}

extern "C" void kernel_launch(void* const* d_in, const int* in_sizes, int n_in,
                              void* d_out, int out_size, void* d_ws, size_t ws_size,
                              hipStream_t stream) {
  const float* Q = (const float*)d_in[0];
  const float* K = (const float*)d_in[1];
  const float* V = (const float*)d_in[2];
  // d_in[3] (mask) is statically causal -> not read.
  float* outO = (float*)d_out;
  float* outP = outO + (size_t)32 * S_LEN * 64;  // after [B,H,S,D] output
  sdpa_kernel<<<dim3(32 * 32), dim3(256), 0, stream>>>(Q, K, V, outO, outP);
}

// Round 7
// 214.387 us; speedup vs baseline: 1.0760x; 1.0760x over previous
//
#include <hip/hip_runtime.h>
#include <math.h>

// Causal SDPA, B=4 H=8 S=2048 D=64, scale = 1/sqrt(512)  (HIDDEN_SIZE=512).
// d_out (fp32): [B,H,S,D] output O followed by [B,H,S,S] attn probs P.
// Inputs fp32. mask input ignored (statically causal, triu k=1).
//
// Swapped QK^T (mfma(K,Q) -> S^T): lane owns one q-row -> float4 P stores,
// 2-shuffle softmax reduce. This round: ALL output stores non-temporal so
// the 537 MB P-stream doesn't evict K/V from L2/LLC (re-read theory).

#define S_LEN 2048
#define SCALE 0.04419417382415922f  // 1/sqrt(512)

typedef __attribute__((ext_vector_type(8))) short bf16x8;
typedef __attribute__((ext_vector_type(4))) short bf16x4;
typedef __attribute__((ext_vector_type(4))) float f32x4;

__device__ __forceinline__ short f2bf(float f) {
  unsigned u = __builtin_bit_cast(unsigned, f);
  u = (u + 0x7FFFu + ((u >> 16) & 1u)) >> 16;
  return (short)u;
}

__device__ __forceinline__ bf16x8 pack8(float4 a, float4 b) {
  bf16x8 t;
  t[0] = f2bf(a.x); t[1] = f2bf(a.y); t[2] = f2bf(a.z); t[3] = f2bf(a.w);
  t[4] = f2bf(b.x); t[5] = f2bf(b.y); t[6] = f2bf(b.z); t[7] = f2bf(b.w);
  return t;
}

__device__ __forceinline__ void nt_store4(float* p, float x, float y, float z2, float w2) {
  f32x4 v; v[0] = x; v[1] = y; v[2] = z2; v[3] = w2;
  __builtin_nontemporal_store(v, (f32x4*)p);   // ext-vector type: builtin-legal
}

// LDS rows padded to 72 halfs (144 B): 16B-aligned rows, bank-group rotation.
__global__ __launch_bounds__(256, 2)
void sdpa_kernel(const float* Q, const float* K, const float* V,
                 float* outO, float* outP)
{
  __shared__ __align__(16) short ldsK[64][72];      // K tile   [k][d]
  __shared__ __align__(16) short ldsV[64][72];      // V^T tile [d][k]
  __shared__ __align__(16) short ldsP[4][16][72];   // per-wave P tile [q][k]

  const int tid  = threadIdx.x;
  const int lane = tid & 63;
  const int w    = tid >> 6;
  const int lrow = lane & 15;   // q-row lane index (S^T cols / O d-cols)
  const int lgrp = lane >> 4;

  // heavy q-tiles first: no load-imbalance tail
  const int qt = 31 - (blockIdx.x >> 5);
  const int bh = blockIdx.x & 31;
  const int q0 = qt << 6;
  const int qrow = q0 + (w << 4) + lrow;   // this lane's q row

  // staging map: thread covers tile row sr, 16 floats from col sc
  const int sr = tid & 63;
  const int sc = (tid >> 6) << 4;

  // Q fragment (B operand of S^T = K*Q^T): lane holds Q[qrow][ks*32+lgrp*8..+7]
  bf16x8 qf[2];
  {
    const float* qb = Q + ((size_t)(bh * S_LEN + qrow)) * 64;
#pragma unroll
    for (int ks = 0; ks < 2; ++ks) {
      const float* p = qb + ks * 32 + lgrp * 8;
      qf[ks] = pack8(*(const float4*)p, *(const float4*)(p + 4));
    }
  }

  float m_run = -INFINITY;
  float l_run = 0.f;

  // ================= pass 1: exact row max + denominator =================
  for (int kt = 0; kt <= qt; ++kt) {
    __syncthreads();
    {
      const float* src = K + ((size_t)(bh * S_LEN + (kt << 6) + sr)) * 64 + sc;
      float4 a0 = ((const float4*)src)[0];
      float4 a1 = ((const float4*)src)[1];
      float4 a2 = ((const float4*)src)[2];
      float4 a3 = ((const float4*)src)[3];
      *(bf16x8*)&ldsK[sr][sc]     = pack8(a0, a1);
      *(bf16x8*)&ldsK[sr][sc + 8] = pack8(a2, a3);
    }
    __syncthreads();

    f32x4 acc[4];
#pragma unroll
    for (int nt = 0; nt < 4; ++nt) {
      f32x4 a = {0.f, 0.f, 0.f, 0.f};
#pragma unroll
      for (int ks = 0; ks < 2; ++ks) {
        bf16x8 kfrag = *(const bf16x8*)&ldsK[nt * 16 + lrow][ks * 32 + lgrp * 8];
        a = __builtin_amdgcn_mfma_f32_16x16x32_bf16(kfrag, qf[ks], a, 0, 0, 0);
      }
      acc[nt] = a;
    }

    // scale (+ mask only on diagonal tile); lane's 16 regs all belong to qrow
    if (kt == qt) {
#pragma unroll
      for (int nt = 0; nt < 4; ++nt)
#pragma unroll
        for (int rg = 0; rg < 4; ++rg) {
          const int col = (kt << 6) + nt * 16 + (lgrp << 2) + rg;
          acc[nt][rg] = (col > qrow) ? -INFINITY : acc[nt][rg] * SCALE;
        }
    } else {
#pragma unroll
      for (int nt = 0; nt < 4; ++nt)
#pragma unroll
        for (int rg = 0; rg < 4; ++rg) acc[nt][rg] *= SCALE;
    }

    float tm = -INFINITY;
#pragma unroll
    for (int nt = 0; nt < 4; ++nt)
#pragma unroll
      for (int rg = 0; rg < 4; ++rg) tm = fmaxf(tm, acc[nt][rg]);
    tm = fmaxf(tm, __shfl_xor(tm, 16));
    tm = fmaxf(tm, __shfl_xor(tm, 32));
    const float nm = fmaxf(m_run, tm);

    float ps = 0.f;
#pragma unroll
    for (int nt = 0; nt < 4; ++nt)
#pragma unroll
      for (int rg = 0; rg < 4; ++rg) ps += __expf(acc[nt][rg] - nm);
    ps += __shfl_xor(ps, 16);
    ps += __shfl_xor(ps, 32);

    l_run = l_run * __expf(m_run - nm) + ps;
    m_run = nm;
  }

  const float inv_l = 1.f / l_run;

  f32x4 oacc[4];
#pragma unroll
  for (int nt = 0; nt < 4; ++nt) oacc[nt] = (f32x4){0.f, 0.f, 0.f, 0.f};

  const size_t pbase = (size_t)bh * S_LEN * S_LEN + (size_t)qrow * S_LEN;

  // ================= pass 2: probs, attn store, PV =================
  for (int kt = 0; kt <= qt; ++kt) {
    __syncthreads();
    {
      const float* srcK = K + ((size_t)(bh * S_LEN + (kt << 6) + sr)) * 64 + sc;
      float4 a0 = ((const float4*)srcK)[0];
      float4 a1 = ((const float4*)srcK)[1];
      float4 a2 = ((const float4*)srcK)[2];
      float4 a3 = ((const float4*)srcK)[3];
      *(bf16x8*)&ldsK[sr][sc]     = pack8(a0, a1);
      *(bf16x8*)&ldsK[sr][sc + 8] = pack8(a2, a3);

      const float* srcV = V + ((size_t)(bh * S_LEN + (kt << 6) + sr)) * 64 + sc;
      float4 b0 = ((const float4*)srcV)[0];
      float4 b1 = ((const float4*)srcV)[1];
      float4 b2 = ((const float4*)srcV)[2];
      float4 b3 = ((const float4*)srcV)[3];
      const float vv[16] = {b0.x, b0.y, b0.z, b0.w, b1.x, b1.y, b1.z, b1.w,
                            b2.x, b2.y, b2.z, b2.w, b3.x, b3.y, b3.z, b3.w};
#pragma unroll
      for (int j = 0; j < 16; ++j) ldsV[sc + j][sr] = f2bf(vv[j]);  // transpose
    }
    __syncthreads();

    f32x4 acc[4];
#pragma unroll
    for (int nt = 0; nt < 4; ++nt) {
      f32x4 a = {0.f, 0.f, 0.f, 0.f};
#pragma unroll
      for (int ks = 0; ks < 2; ++ks) {
        bf16x8 kfrag = *(const bf16x8*)&ldsK[nt * 16 + lrow][ks * 32 + lgrp * 8];
        a = __builtin_amdgcn_mfma_f32_16x16x32_bf16(kfrag, qf[ks], a, 0, 0, 0);
      }
      acc[nt] = a;
    }

    if (kt == qt) {
#pragma unroll
      for (int nt = 0; nt < 4; ++nt)
#pragma unroll
        for (int rg = 0; rg < 4; ++rg) {
          const int col = (kt << 6) + nt * 16 + (lgrp << 2) + rg;
          acc[nt][rg] = (col > qrow) ? -INFINITY : acc[nt][rg] * SCALE;
        }
    } else {
#pragma unroll
      for (int nt = 0; nt < 4; ++nt)
#pragma unroll
        for (int rg = 0; rg < 4; ++rg) acc[nt][rg] *= SCALE;
    }

    // probabilities: non-temporal float4 global store + b64 LDS store per nt
#pragma unroll
    for (int nt = 0; nt < 4; ++nt) {
      float p0 = __expf(acc[nt][0] - m_run) * inv_l;
      float p1 = __expf(acc[nt][1] - m_run) * inv_l;
      float p2 = __expf(acc[nt][2] - m_run) * inv_l;
      float p3 = __expf(acc[nt][3] - m_run) * inv_l;
      nt_store4(outP + pbase + (kt << 6) + nt * 16 + (lgrp << 2), p0, p1, p2, p3);
      bf16x4 pb;
      pb[0] = f2bf(p0); pb[1] = f2bf(p1);
      pb[2] = f2bf(p2); pb[3] = f2bf(p3);
      *(bf16x4*)&ldsP[w][lrow][nt * 16 + (lgrp << 2)] = pb;
    }

    // PV: A = own-wave P tile (16q x 64k), B = V^T tile (same-wave LDS
    // write->read; ldsP[w] is wave-private, ordered by lgkmcnt).
#pragma unroll
    for (int nt = 0; nt < 4; ++nt) {
#pragma unroll
      for (int ks = 0; ks < 2; ++ks) {
        bf16x8 pa = *(const bf16x8*)&ldsP[w][lrow][ks * 32 + lgrp * 8];
        bf16x8 vb = *(const bf16x8*)&ldsV[nt * 16 + lrow][ks * 32 + lgrp * 8];
        oacc[nt] = __builtin_amdgcn_mfma_f32_16x16x32_bf16(pa, vb, oacc[nt], 0, 0, 0);
      }
    }
  }

  // ---- zero the strictly-masked column range (cols >= (qt+1)*64) ----
  {
    const int kz = (qt + 1) << 6;
    if (kz < S_LEN) {
      for (int row = 0; row < 64; ++row) {
        const size_t base = (size_t)bh * S_LEN * S_LEN + (size_t)(q0 + row) * S_LEN;
        for (int c = kz + (tid << 2); c < S_LEN; c += 256 * 4) {
          nt_store4(outP + base + c, 0.f, 0.f, 0.f, 0.f);
        }
      }
    }
  }

  // ---- write O (fp32): O row = q0+16w+4*lgrp+rg, col d = nt*16+lrow ----
#pragma unroll
  for (int nt = 0; nt < 4; ++nt) {
#pragma unroll
    for (int rg = 0; rg < 4; ++rg) {
      const int rl = (lgrp << 2) + rg;
      const int d  = nt * 16 + lrow;
      __builtin_nontemporal_store(
          oacc[nt][rg],
          outO + ((size_t)(bh * S_LEN + q0 + (w << 4) + rl)) * 64 + d);
    }
  }
}

extern "C" void kernel_launch(void* const* d_in, const int* in_sizes, int n_in,
                              void* d_out, int out_size, void* d_ws, size_t ws_size,
                              hipStream_t stream) {
  const float* Q = (const float*)d_in[0];
  const float* K = (const float*)d_in[1];
  const float* V = (const float*)d_in[2];
  // d_in[3] (mask) is statically causal -> not read.
  float* outO = (float*)d_out;
  float* outP = outO + (size_t)32 * S_LEN * 64;  // after [B,H,S,D] output
  sdpa_kernel<<<dim3(32 * 32), dim3(256), 0, stream>>>(Q, K, V, outO, outP);
}